// Round 1
// baseline (282.438 us; speedup 1.0000x reference)
//
#include <hip/hip_runtime.h>
#include <hip/hip_bf16.h>

#define Bb 32
#define Ss 2048
#define Hh 1024

typedef __attribute__((ext_vector_type(4))) float f32x4;
typedef __attribute__((ext_vector_type(8))) short s16x8;

#define GAS const __attribute__((address_space(1))) unsigned int
#define LAS __attribute__((address_space(3))) unsigned int

__device__ __forceinline__ unsigned short f2bf(float x) {
  unsigned int u = __float_as_uint(x);
  u = (u + 0x7fffu + ((u >> 16) & 1u)) >> 16;
  return (unsigned short)u;
}

// ---- fp32 -> bf16 conversion, 8 elems/thread/iter ----
__global__ void cvt_bf16_kernel(const float* __restrict__ in,
                                unsigned short* __restrict__ out, int n8) {
  int idx = blockIdx.x * blockDim.x + threadIdx.x;
  int stride = gridDim.x * blockDim.x;
  for (int i = idx; i < n8; i += stride) {
    const float4* p = reinterpret_cast<const float4*>(in) + 2 * (size_t)i;
    float4 a = p[0];
    float4 b = p[1];
    union { unsigned short u[8]; uint4 q; } r;
    r.u[0] = f2bf(a.x); r.u[1] = f2bf(a.y); r.u[2] = f2bf(a.z); r.u[3] = f2bf(a.w);
    r.u[4] = f2bf(b.x); r.u[5] = f2bf(b.y); r.u[6] = f2bf(b.z); r.u[7] = f2bf(b.w);
    reinterpret_cast<uint4*>(out)[i] = r.q;
  }
}

// ---- dec_feature[b][o] = dot(dh[b], W_dec[o]) + b_dec[o], fp32, wave per (b,o) ----
__global__ void dec_feat_kernel(const float* __restrict__ dh,
                                const float* __restrict__ Wd,
                                const float* __restrict__ bd,
                                float* __restrict__ out) {
  int gw = blockIdx.x * 4 + (threadIdx.x >> 6);
  int lane = threadIdx.x & 63;
  int b = gw >> 10;
  int o = gw & 1023;
  const float4* x = reinterpret_cast<const float4*>(dh + (size_t)b * Hh);
  const float4* w = reinterpret_cast<const float4*>(Wd + (size_t)o * Hh);
  float acc = 0.f;
#pragma unroll
  for (int it = 0; it < 4; ++it) {
    float4 xa = x[lane + it * 64];
    float4 wa = w[lane + it * 64];
    acc += xa.x * wa.x + xa.y * wa.y + xa.z * wa.z + xa.w * wa.w;
  }
#pragma unroll
  for (int m = 1; m < 64; m <<= 1) acc += __shfl_xor(acc, m, 64);
  if (lane == 0) out[gw] = acc + bd[o];
}

// ---- fused GEMM (bf16 MFMA) + tanh + v-dot partial reduce ----
// C[s,o] = sum_h A[s,h]*W[o,h]; score = tanh(C + dec[b,o] + cov[b,s]*wcov[o]);
// partial[s] += sum_o score*v[o]  (atomicAdd)
__global__ void __launch_bounds__(256, 2)
gemm_tanh_kernel(const unsigned short* __restrict__ A,   // [65536,1024] bf16
                 const unsigned short* __restrict__ W,   // [1024,1024] bf16
                 const float* __restrict__ decf,         // [32,1024]
                 const float* __restrict__ cov,          // [32,2048]
                 const float* __restrict__ wcov,         // [1024]
                 const float* __restrict__ v,            // [1024]
                 float* __restrict__ scores) {           // [32,2048]
  __shared__ unsigned short lds[2 * 8192];  // 2 bufs x (A 128x32 + B 128x32) bf16 = 32KB

  int bid = blockIdx.x;
  // XCD-bijective swizzle: 4096 blocks, 8 XCDs -> each XCD sweeps o fast, s slow
  int swz = (bid & 7) * 512 + (bid >> 3);
  int s_tile = swz >> 3;   // 0..511
  int o_tile = swz & 7;    // 0..7

  const int tid = threadIdx.x;
  const int lane = tid & 63;
  const int wid = tid >> 6;
  const int wr = wid >> 1;          // wave row (0..1) -> 64 s-rows each
  const int wc = wid & 1;           // wave col (0..1) -> 64 o-cols each
  const int fr = lane & 15;         // fragment row/col within 16
  const int fk = (lane >> 4) * 8;   // k offset (bf16 elems)

  const size_t a_base = (size_t)s_tile * 128 * 1024;
  const size_t b_base = (size_t)o_tile * 128 * 1024;
  const int st_row = tid >> 2;           // 0..63
  const int st_k = (tid & 3) * 8;        // 0,8,16,24
  const unsigned short* gA = A + a_base + (size_t)st_row * 1024 + st_k;
  const unsigned short* gB = W + b_base + (size_t)st_row * 1024 + st_k;
  unsigned short* la = lds + tid * 8;    // linear lane order (wave-uniform base + lane*16)

#define STAGE(buf, kt) do {                                                        \
    const unsigned short* _ga = gA + (size_t)(kt) * 32;                            \
    const unsigned short* _gb = gB + (size_t)(kt) * 32;                            \
    unsigned short* _la = la + (buf) * 8192;                                       \
    __builtin_amdgcn_global_load_lds((GAS*)(_ga),         (LAS*)(_la),        16, 0, 0); \
    __builtin_amdgcn_global_load_lds((GAS*)(_ga + 65536), (LAS*)(_la + 2048), 16, 0, 0); \
    __builtin_amdgcn_global_load_lds((GAS*)(_gb),         (LAS*)(_la + 4096), 16, 0, 0); \
    __builtin_amdgcn_global_load_lds((GAS*)(_gb + 65536), (LAS*)(_la + 6144), 16, 0, 0); \
  } while (0)

  f32x4 acc[4][4];
#pragma unroll
  for (int i = 0; i < 4; ++i)
#pragma unroll
    for (int j = 0; j < 4; ++j) acc[i][j] = (f32x4){0.f, 0.f, 0.f, 0.f};

  STAGE(0, 0);
  __syncthreads();
  int buf = 0;
  const unsigned short* baseA0 = lds + (size_t)(wr * 64 + fr) * 32 + fk;
  const unsigned short* baseB0 = lds + 4096 + (size_t)(wc * 64 + fr) * 32 + fk;

  for (int kt = 0; kt < 32; ++kt) {
    if (kt < 31) STAGE(buf ^ 1, kt + 1);  // prefetch next K-tile (overlaps MFMA)
    const unsigned short* bA = baseA0 + buf * 8192;
    const unsigned short* bB = baseB0 + buf * 8192;
    s16x8 af[4], bfr[4];
#pragma unroll
    for (int i = 0; i < 4; ++i) af[i] = *reinterpret_cast<const s16x8*>(bA + i * 512);
#pragma unroll
    for (int j = 0; j < 4; ++j) bfr[j] = *reinterpret_cast<const s16x8*>(bB + j * 512);
#pragma unroll
    for (int i = 0; i < 4; ++i)
#pragma unroll
      for (int j = 0; j < 4; ++j)
        acc[i][j] = __builtin_amdgcn_mfma_f32_16x16x32_bf16(af[i], bfr[j], acc[i][j], 0, 0, 0);
    __syncthreads();  // drains vmcnt (next tile staged) + all waves done reading buf
    buf ^= 1;
  }
#undef STAGE

  // epilogue: C/D layout col=lane&15, row=(lane>>4)*4+reg  [m89-verified]
  const int row_base = s_tile * 128 + wr * 64 + (lane >> 4) * 4;  // flat b*2048+s
  const int o_base_g = o_tile * 128 + wc * 64 + fr;
  const int bb = (s_tile * 128) >> 11;  // batch (constant per block: 2048 % 128 == 0)

  float vv[4], dv[4], wv[4];
#pragma unroll
  for (int j = 0; j < 4; ++j) {
    int o = o_base_g + j * 16;
    vv[j] = v[o];
    wv[j] = wcov[o];
    dv[j] = decf[bb * 1024 + o];
  }

#pragma unroll
  for (int i = 0; i < 4; ++i) {
#pragma unroll
    for (int r = 0; r < 4; ++r) {
      int s_flat = row_base + i * 16 + r;
      float c = cov[s_flat];
      float sum = 0.f;
#pragma unroll
      for (int j = 0; j < 4; ++j) {
        float x = acc[i][j][r] + dv[j] + c * wv[j];
        sum += tanhf(x) * vv[j];
      }
      // reduce over the 16 lanes of this row group (cols)
      sum += __shfl_xor(sum, 1, 64);
      sum += __shfl_xor(sum, 2, 64);
      sum += __shfl_xor(sum, 4, 64);
      sum += __shfl_xor(sum, 8, 64);
      if (fr == 0) atomicAdd(&scores[s_flat], sum);
    }
  }
}

// ---- softmax over S=2048 per batch row ----
__global__ void softmax_kernel(const float* __restrict__ scores, float* __restrict__ out) {
  int b = blockIdx.x;
  int tid = threadIdx.x;
  int lane = tid & 63, w = tid >> 6;
  const float* row = scores + (size_t)b * Ss;
  float vals[8];
#pragma unroll
  for (int k = 0; k < 8; ++k) vals[k] = row[tid + k * 256];
  float m = vals[0];
#pragma unroll
  for (int k = 1; k < 8; ++k) m = fmaxf(m, vals[k]);
#pragma unroll
  for (int off = 1; off < 64; off <<= 1) m = fmaxf(m, __shfl_xor(m, off, 64));
  __shared__ float sm[4], ss[4];
  if (lane == 0) sm[w] = m;
  __syncthreads();
  m = fmaxf(fmaxf(sm[0], sm[1]), fmaxf(sm[2], sm[3]));
  float s = 0.f;
#pragma unroll
  for (int k = 0; k < 8; ++k) { vals[k] = __expf(vals[k] - m); s += vals[k]; }
#pragma unroll
  for (int off = 1; off < 64; off <<= 1) s += __shfl_xor(s, off, 64);
  if (lane == 0) ss[w] = s;
  __syncthreads();
  s = ss[0] + ss[1] + ss[2] + ss[3];
  float inv = 1.f / s;
#pragma unroll
  for (int k = 0; k < 8; ++k) out[(size_t)b * Ss + tid + k * 256] = vals[k] * inv;
}

extern "C" void kernel_launch(void* const* d_in, const int* in_sizes, int n_in,
                              void* d_out, int out_size, void* d_ws, size_t ws_size,
                              hipStream_t stream) {
  const float* dh    = (const float*)d_in[0];  // [32,1,1024]
  const float* enc   = (const float*)d_in[1];  // [32,2048,1024]
  const float* cov   = (const float*)d_in[2];  // [32,2048]
  const float* W_enc = (const float*)d_in[3];  // [1024,1024]
  const float* W_dec = (const float*)d_in[4];  // [1024,1024]
  const float* b_dec = (const float*)d_in[5];  // [1024]
  const float* w_cov = (const float*)d_in[6];  // [1024]
  const float* v     = (const float*)d_in[7];  // [1024]
  float* out = (float*)d_out;

  char* ws = (char*)d_ws;
  unsigned short* A_bf  = (unsigned short*)ws;                   // 128 MB
  unsigned short* W_bf  = (unsigned short*)(ws + 134217728);     // 2 MB
  float*          decf  = (float*)(ws + 136314880);              // 128 KB
  float*          score = (float*)(ws + 136445952);              // 256 KB

  hipMemsetAsync(score, 0, (size_t)Bb * Ss * sizeof(float), stream);
  cvt_bf16_kernel<<<4096, 256, 0, stream>>>(enc, A_bf, (Bb * Ss * Hh) / 8);
  cvt_bf16_kernel<<<512, 256, 0, stream>>>(W_enc, W_bf, (Hh * Hh) / 8);
  dec_feat_kernel<<<(Bb * Hh) / 4, 256, 0, stream>>>(dh, W_dec, b_dec, decf);
  gemm_tanh_kernel<<<4096, 256, 0, stream>>>(A_bf, W_bf, decf, cov, w_cov, v, score);
  softmax_kernel<<<Bb, 256, 0, stream>>>(score, out);
}